// Round 1
// baseline (277.552 us; speedup 1.0000x reference)
//
#include <hip/hip_runtime.h>
#include <cstdint>
#include <cstddef>

// B=8, N=1024, E=768, H=12, HD=64.  BH = 96.
// scale = HD^-0.5 = 0.125; fold 0.125*log2(e) into Q so softmax uses exp2.
#define QSCALE 0.18033688011112042f

typedef __bf16 bf16x8 __attribute__((ext_vector_type(8)));
typedef float floatx4 __attribute__((ext_vector_type(4)));

static __device__ __forceinline__ uint16_t f2bf(float f) {
    uint32_t u = __builtin_bit_cast(uint32_t, f);
    u += 0x7FFFu + ((u >> 16) & 1u);      // RNE
    return (uint16_t)(u >> 16);
}

static __device__ __forceinline__ bf16x8 ld_frag(const uint16_t* p) {
    uint4 u = *(const uint4*)p;           // 16B aligned by construction
    return __builtin_bit_cast(bf16x8, u);
}

// ---------------- fp32 -> bf16 cast, 8 elems/thread ----------------
__global__ __launch_bounds__(256) void cast_bf16_kernel(
    const float* __restrict__ in, uint16_t* __restrict__ out, int n8)
{
    int i = blockIdx.x * 256 + threadIdx.x;
    if (i >= n8) return;
    const float4* p = (const float4*)in + (size_t)2 * i;
    float4 a = p[0], b = p[1];
    uint32_t w0 = (uint32_t)f2bf(a.x) | ((uint32_t)f2bf(a.y) << 16);
    uint32_t w1 = (uint32_t)f2bf(a.z) | ((uint32_t)f2bf(a.w) << 16);
    uint32_t w2 = (uint32_t)f2bf(b.x) | ((uint32_t)f2bf(b.y) << 16);
    uint32_t w3 = (uint32_t)f2bf(b.z) | ((uint32_t)f2bf(b.w) << 16);
    uint4 v; v.x = w0; v.y = w1; v.z = w2; v.w = w3;
    *((uint4*)out + i) = v;
}

// ---------------- QKV GEMM: [8192,768] x [2304,768]^T + bias ----------------
// 128x128 tile, BK=32, 4 waves in 2x2, each wave 64x64 via 4x4 mfma 16x16x32.
// Epilogue scatters: Q (scaled) -> [96][1024][64], K -> [96][1024][64],
//                    V -> transposed [96][64][1024].
__global__ __launch_bounds__(256) void gemm_qkv_kernel(
    const uint16_t* __restrict__ X,    // [8192][768] bf16
    const uint16_t* __restrict__ W,    // [2304][768] bf16
    const float* __restrict__ bias,    // [2304]
    uint16_t* __restrict__ Qb, uint16_t* __restrict__ Kb, uint16_t* __restrict__ Vtb)
{
    __shared__ __align__(16) uint16_t As[128][40];   // +8 pad: 2-way-max bank alias
    __shared__ __align__(16) uint16_t Bs[128][40];
    const int tid = threadIdx.x;
    const int wave = tid >> 6, lane = tid & 63;
    const int L = lane & 15, quad = lane >> 4;
    const int wM = (wave >> 1) * 64, wN = (wave & 1) * 64;
    const int bm = blockIdx.x * 128;   // M tile (64 tiles)
    const int bn = blockIdx.y * 128;   // N tile (18 tiles)

    floatx4 zero4 = {0.f, 0.f, 0.f, 0.f};
    floatx4 acc[4][4];
    #pragma unroll
    for (int i = 0; i < 4; ++i)
        #pragma unroll
        for (int j = 0; j < 4; ++j) acc[i][j] = zero4;

    const int srow = tid >> 2;          // 0..63
    const int scol = (tid & 3) * 8;     // 0,8,16,24
    const uint16_t* xp0 = X + (size_t)(bm + srow) * 768 + scol;
    const uint16_t* xp1 = xp0 + (size_t)64 * 768;
    const uint16_t* wp0 = W + (size_t)(bn + srow) * 768 + scol;
    const uint16_t* wp1 = wp0 + (size_t)64 * 768;

    for (int k0 = 0; k0 < 768; k0 += 32) {
        __syncthreads();
        uint4 a0 = *(const uint4*)(xp0 + k0);
        uint4 a1 = *(const uint4*)(xp1 + k0);
        uint4 b0 = *(const uint4*)(wp0 + k0);
        uint4 b1 = *(const uint4*)(wp1 + k0);
        *(uint4*)&As[srow][scol]      = a0;
        *(uint4*)&As[srow + 64][scol] = a1;
        *(uint4*)&Bs[srow][scol]      = b0;
        *(uint4*)&Bs[srow + 64][scol] = b1;
        __syncthreads();
        bf16x8 af[4], bfr[4];
        #pragma unroll
        for (int mi = 0; mi < 4; ++mi) af[mi]  = ld_frag(&As[wM + mi * 16 + L][quad * 8]);
        #pragma unroll
        for (int ni = 0; ni < 4; ++ni) bfr[ni] = ld_frag(&Bs[wN + ni * 16 + L][quad * 8]);
        #pragma unroll
        for (int mi = 0; mi < 4; ++mi)
            #pragma unroll
            for (int ni = 0; ni < 4; ++ni)
                acc[mi][ni] = __builtin_amdgcn_mfma_f32_16x16x32_bf16(
                    af[mi], bfr[ni], acc[mi][ni], 0, 0, 0);
    }

    const int part = bn / 768;          // uniform per block (0=Q,1=K,2=V)
    #pragma unroll
    for (int ni = 0; ni < 4; ++ni) {
        int col = bn + wN + ni * 16 + L;
        int c = col - part * 768;
        int h = c >> 6, hd = c & 63;
        float bv = bias[col];
        #pragma unroll
        for (int mi = 0; mi < 4; ++mi) {
            #pragma unroll
            for (int r = 0; r < 4; ++r) {
                int m = bm + wM + mi * 16 + quad * 4 + r;   // C row = (lane>>4)*4+reg
                int b = m >> 10, ns = m & 1023;
                int bh = b * 12 + h;
                float v = acc[mi][ni][r] + bv;
                if (part == 0)      Qb[((size_t)bh * 1024 + ns) * 64 + hd] = f2bf(v * QSCALE);
                else if (part == 1) Kb[((size_t)bh * 1024 + ns) * 64 + hd] = f2bf(v);
                else                Vtb[((size_t)bh * 64 + hd) * 1024 + ns] = f2bf(v);
            }
        }
    }
}

// ---------------- Flash attention ----------------
// grid (16 q-tiles, 96 heads); block 256 = 4 waves; wave owns 16 q-rows.
__global__ __launch_bounds__(256) void attn_kernel(
    const uint16_t* __restrict__ Qb,   // [96][1024][64] bf16, pre-scaled
    const uint16_t* __restrict__ Kb,   // [96][1024][64] bf16
    const uint16_t* __restrict__ Vtb,  // [96][64][1024] bf16 (transposed)
    uint16_t* __restrict__ Ob)         // [8192][768] bf16
{
    __shared__ __align__(16) uint16_t Ks[64][72];      // [key][hd], +8 pad
    __shared__ __align__(16) uint16_t Vs[64][72];      // [hd][key], +8 pad
    __shared__ __align__(16) uint16_t Ps[4][16][72];   // wave-private P staging

    const int tid = threadIdx.x;
    const int wave = tid >> 6, lane = tid & 63;
    const int L = lane & 15, quad = lane >> 4;
    const int qt = blockIdx.x;         // 0..15  (consecutive blocks share a head -> L2)
    const int bh = blockIdx.y;         // 0..95
    const int b = bh / 12, h = bh - b * 12;

    // A-operand Q fragments (held in regs whole kernel): A[m=L][k=quad*8+j]
    const uint16_t* qrow = Qb + ((size_t)bh * 1024 + qt * 64 + wave * 16 + L) * 64;
    bf16x8 aq0 = ld_frag(qrow + quad * 8);
    bf16x8 aq1 = ld_frag(qrow + 32 + quad * 8);

    floatx4 zero4 = {0.f, 0.f, 0.f, 0.f};
    floatx4 accO[4] = {zero4, zero4, zero4, zero4};
    float mrow[4] = {-__builtin_inff(), -__builtin_inff(), -__builtin_inff(), -__builtin_inff()};
    float lrow[4] = {0.f, 0.f, 0.f, 0.f};

    const int sr = tid >> 3;           // 0..31
    const int sc = (tid & 7) * 8;      // 0..56
    const uint16_t* kbase = Kb + (size_t)bh * 65536;
    const uint16_t* vbase = Vtb + (size_t)bh * 65536;

    for (int j = 0; j < 16; ++j) {
        __syncthreads();
        uint4 k0 = *(const uint4*)(kbase + j * 4096 + tid * 8);          // rows 0..31
        uint4 k1 = *(const uint4*)(kbase + j * 4096 + 2048 + tid * 8);   // rows 32..63
        uint4 v0 = *(const uint4*)(vbase + (size_t)sr * 1024 + j * 64 + sc);
        uint4 v1 = *(const uint4*)(vbase + (size_t)(sr + 32) * 1024 + j * 64 + sc);
        *(uint4*)&Ks[sr][sc]      = k0;
        *(uint4*)&Ks[sr + 32][sc] = k1;
        *(uint4*)&Vs[sr][sc]      = v0;
        *(uint4*)&Vs[sr + 32][sc] = v1;
        __syncthreads();

        // S = Q K^T : per wave 16q x 64k. B[k][n]=K[key=n][hd=k] -> row-read of Ks.
        floatx4 s[4];
        #pragma unroll
        for (int ni = 0; ni < 4; ++ni) {
            bf16x8 bk0 = ld_frag(&Ks[ni * 16 + L][quad * 8]);
            bf16x8 bk1 = ld_frag(&Ks[ni * 16 + L][32 + quad * 8]);
            floatx4 z = zero4;
            z     = __builtin_amdgcn_mfma_f32_16x16x32_bf16(aq0, bk0, z, 0, 0, 0);
            s[ni] = __builtin_amdgcn_mfma_f32_16x16x32_bf16(aq1, bk1, z, 0, 0, 0);
        }

        // Online softmax. Lane holds rows 4*quad+r (r=0..3), col = ni*16+L.
        #pragma unroll
        for (int r = 0; r < 4; ++r) {
            float mx = fmaxf(fmaxf(s[0][r], s[1][r]), fmaxf(s[2][r], s[3][r]));
            mx = fmaxf(mx, __shfl_xor(mx, 1));
            mx = fmaxf(mx, __shfl_xor(mx, 2));
            mx = fmaxf(mx, __shfl_xor(mx, 4));
            mx = fmaxf(mx, __shfl_xor(mx, 8));
            float mnew = fmaxf(mrow[r], mx);
            float alpha = exp2f(mrow[r] - mnew);
            mrow[r] = mnew;
            float p0 = exp2f(s[0][r] - mnew);
            float p1 = exp2f(s[1][r] - mnew);
            float p2 = exp2f(s[2][r] - mnew);
            float p3 = exp2f(s[3][r] - mnew);
            s[0][r] = p0; s[1][r] = p1; s[2][r] = p2; s[3][r] = p3;
            float sum = (p0 + p1) + (p2 + p3);
            sum += __shfl_xor(sum, 1);
            sum += __shfl_xor(sum, 2);
            sum += __shfl_xor(sum, 4);
            sum += __shfl_xor(sum, 8);
            lrow[r] = lrow[r] * alpha + sum;
            accO[0][r] *= alpha; accO[1][r] *= alpha;
            accO[2][r] *= alpha; accO[3][r] *= alpha;
        }

        // P: C-layout -> A-layout via wave-private LDS (no barrier needed).
        #pragma unroll
        for (int r = 0; r < 4; ++r)
            #pragma unroll
            for (int ni = 0; ni < 4; ++ni)
                Ps[wave][quad * 4 + r][ni * 16 + L] = f2bf(s[ni][r]);

        bf16x8 ap0 = ld_frag(&Ps[wave][L][quad * 8]);
        bf16x8 ap1 = ld_frag(&Ps[wave][L][32 + quad * 8]);
        // O += P V : B[k][n]=V[key=k][hd=n]=Vs[n][k] -> row-read of Vs.
        #pragma unroll
        for (int ni = 0; ni < 4; ++ni) {
            bf16x8 bv0 = ld_frag(&Vs[ni * 16 + L][quad * 8]);
            bf16x8 bv1 = ld_frag(&Vs[ni * 16 + L][32 + quad * 8]);
            accO[ni] = __builtin_amdgcn_mfma_f32_16x16x32_bf16(ap0, bv0, accO[ni], 0, 0, 0);
            accO[ni] = __builtin_amdgcn_mfma_f32_16x16x32_bf16(ap1, bv1, accO[ni], 0, 0, 0);
        }
    }

    float inv[4];
    #pragma unroll
    for (int r = 0; r < 4; ++r) inv[r] = 1.f / lrow[r];
    // out[b, q, h*64+hd]  (row-major [8192][768], ready as next GEMM input)
    uint16_t* orow = Ob + ((size_t)b * 1024 + qt * 64 + wave * 16) * 768 + h * 64;
    #pragma unroll
    for (int ni = 0; ni < 4; ++ni)
        #pragma unroll
        for (int r = 0; r < 4; ++r)
            orow[(size_t)(quad * 4 + r) * 768 + ni * 16 + L] = f2bf(accO[ni][r] * inv[r]);
}

// ---------------- Out projection: [8192,768] x [768,768]^T + bias -> fp32 ----------------
__global__ __launch_bounds__(256) void gemm_out_kernel(
    const uint16_t* __restrict__ X,    // [8192][768] bf16 (attention out)
    const uint16_t* __restrict__ W,    // [768][768] bf16
    const float* __restrict__ bias,    // [768]
    float* __restrict__ out)           // [8192][768] fp32
{
    __shared__ __align__(16) uint16_t As[128][40];
    __shared__ __align__(16) uint16_t Bs[128][40];
    const int tid = threadIdx.x;
    const int wave = tid >> 6, lane = tid & 63;
    const int L = lane & 15, quad = lane >> 4;
    const int wM = (wave >> 1) * 64, wN = (wave & 1) * 64;
    const int bm = blockIdx.x * 128;
    const int bn = blockIdx.y * 128;

    floatx4 zero4 = {0.f, 0.f, 0.f, 0.f};
    floatx4 acc[4][4];
    #pragma unroll
    for (int i = 0; i < 4; ++i)
        #pragma unroll
        for (int j = 0; j < 4; ++j) acc[i][j] = zero4;

    const int srow = tid >> 2;
    const int scol = (tid & 3) * 8;
    const uint16_t* xp0 = X + (size_t)(bm + srow) * 768 + scol;
    const uint16_t* xp1 = xp0 + (size_t)64 * 768;
    const uint16_t* wp0 = W + (size_t)(bn + srow) * 768 + scol;
    const uint16_t* wp1 = wp0 + (size_t)64 * 768;

    for (int k0 = 0; k0 < 768; k0 += 32) {
        __syncthreads();
        uint4 a0 = *(const uint4*)(xp0 + k0);
        uint4 a1 = *(const uint4*)(xp1 + k0);
        uint4 b0 = *(const uint4*)(wp0 + k0);
        uint4 b1 = *(const uint4*)(wp1 + k0);
        *(uint4*)&As[srow][scol]      = a0;
        *(uint4*)&As[srow + 64][scol] = a1;
        *(uint4*)&Bs[srow][scol]      = b0;
        *(uint4*)&Bs[srow + 64][scol] = b1;
        __syncthreads();
        bf16x8 af[4], bfr[4];
        #pragma unroll
        for (int mi = 0; mi < 4; ++mi) af[mi]  = ld_frag(&As[wM + mi * 16 + L][quad * 8]);
        #pragma unroll
        for (int ni = 0; ni < 4; ++ni) bfr[ni] = ld_frag(&Bs[wN + ni * 16 + L][quad * 8]);
        #pragma unroll
        for (int mi = 0; mi < 4; ++mi)
            #pragma unroll
            for (int ni = 0; ni < 4; ++ni)
                acc[mi][ni] = __builtin_amdgcn_mfma_f32_16x16x32_bf16(
                    af[mi], bfr[ni], acc[mi][ni], 0, 0, 0);
    }

    #pragma unroll
    for (int ni = 0; ni < 4; ++ni) {
        int col = bn + wN + ni * 16 + L;
        float bv = bias[col];
        #pragma unroll
        for (int mi = 0; mi < 4; ++mi)
            #pragma unroll
            for (int r = 0; r < 4; ++r) {
                int m = bm + wM + mi * 16 + quad * 4 + r;
                out[(size_t)m * 768 + col] = acc[mi][ni][r] + bv;
            }
    }
}

extern "C" void kernel_launch(void* const* d_in, const int* in_sizes, int n_in,
                              void* d_out, int out_size, void* d_ws, size_t ws_size,
                              hipStream_t stream) {
    const float* query = (const float*)d_in[0];   // [8,1024,768]
    const float* qkv_w = (const float*)d_in[1];   // [2304,768]
    const float* qkv_b = (const float*)d_in[2];   // [2304]
    const float* out_w = (const float*)d_in[3];   // [768,768]
    const float* out_b = (const float*)d_in[4];   // [768]
    float* out = (float*)d_out;                   // [8,1024,768] fp32

    uint8_t* ws = (uint8_t*)d_ws;
    // Xb reused as attention-output buffer (X consumed before attn writes it).
    uint16_t* Xb  = (uint16_t*)(ws);                 // 12,582,912 B
    uint16_t* W1b = (uint16_t*)(ws + 12582912);      //  3,538,944 B
    uint16_t* W2b = (uint16_t*)(ws + 16121856);      //  1,179,648 B
    uint16_t* Qb  = (uint16_t*)(ws + 17301504);      // 12,582,912 B
    uint16_t* Kb  = (uint16_t*)(ws + 29884416);      // 12,582,912 B
    uint16_t* Vtb = (uint16_t*)(ws + 42467328);      // 12,582,912 B  (total 55,050,240)
    uint16_t* Ab  = Xb;

    cast_bf16_kernel<<<3072, 256, 0, stream>>>(query, Xb, 786432);
    cast_bf16_kernel<<<864, 256, 0, stream>>>(qkv_w, W1b, 221184);
    cast_bf16_kernel<<<288, 256, 0, stream>>>(out_w, W2b, 73728);
    gemm_qkv_kernel<<<dim3(64, 18), 256, 0, stream>>>(Xb, W1b, qkv_b, Qb, Kb, Vtb);
    attn_kernel<<<dim3(16, 96), 256, 0, stream>>>(Qb, Kb, Vtb, Ab);
    gemm_out_kernel<<<dim3(64, 6), 256, 0, stream>>>(Ab, W2b, out_b, out);
}